// Round 1
// baseline (2827.649 us; speedup 1.0000x reference)
//
#include <hip/hip_runtime.h>

#define HC 256   // H*C
#define NH 4     // heads
#define CH 64    // channels/head

__device__ __forceinline__ void atomicMaxFloat(float* addr, float value) {
  // Works for mixed signs given init bits 0xFFFFFFFF (or -inf):
  // non-negative floats ordered as signed ints; negative floats reverse-ordered as unsigned.
  if (value >= 0.0f) {
    atomicMax((int*)addr, __float_as_int(value));
  } else {
    atomicMin((unsigned int*)addr, __float_as_uint(value));
  }
}

// h = relu(x @ W + b); x:[N,8], W:[8,64], h:[N,64]
__global__ void encoder_kernel(const float* __restrict__ x, const float* __restrict__ W,
                               const float* __restrict__ b, float* __restrict__ h, int N) {
  int idx = blockIdx.x * blockDim.x + threadIdx.x;
  if (idx >= N * 64) return;
  int n = idx >> 6, j = idx & 63;
  const float* xp = x + n * 8;
  float acc = b[j];
#pragma unroll
  for (int k = 0; k < 8; ++k) acc = fmaf(xp[k], W[k * 64 + j], acc);
  h[idx] = fmaxf(acc, 0.0f);
}

// xl = h@Wl + bl, xr = h@Wr + br; h:[N,K], W:[K,256]. Block = 256 thr, 8 nodes/block.
template <int K>
__global__ void lin_lr_kernel(const float* __restrict__ h,
                              const float* __restrict__ Wl, const float* __restrict__ bl,
                              const float* __restrict__ Wr, const float* __restrict__ br,
                              float* __restrict__ xl, float* __restrict__ xr, int N) {
  __shared__ float hs[8][K];
  int n0 = blockIdx.x * 8;
  int j = threadIdx.x;  // 0..255 output column
  int nmax = N - n0; if (nmax > 8) nmax = 8;
  for (int idx = j; idx < nmax * K; idx += 256) {
    int m = idx / K, k = idx % K;  // K is power of 2 -> shifts
    hs[m][k] = h[(size_t)(n0 + m) * K + k];
  }
  __syncthreads();
  float accl[8], accr[8];
  float bjl = bl[j], bjr = br[j];
#pragma unroll
  for (int m = 0; m < 8; ++m) { accl[m] = bjl; accr[m] = bjr; }
  for (int k = 0; k < K; ++k) {
    float wl = Wl[k * 256 + j];
    float wr = Wr[k * 256 + j];
#pragma unroll
    for (int m = 0; m < 8; ++m) {
      accl[m] = fmaf(hs[m][k], wl, accl[m]);
      accr[m] = fmaf(hs[m][k], wr, accr[m]);
    }
  }
  for (int m = 0; m < nmax; ++m) {
    xl[(size_t)(n0 + m) * 256 + j] = accl[m];
    xr[(size_t)(n0 + m) * 256 + j] = accr[m];
  }
}

// One wave per edge: alpha[e,h] = sum_c att[h,c]*leaky(xl[src]+xr[dst]+ea*We), atomicMax amax[dst,h]
__global__ void edge_alpha_kernel(const int* __restrict__ src, const int* __restrict__ dst,
                                  const float* __restrict__ ea,
                                  const float* __restrict__ xl, const float* __restrict__ xr,
                                  const float* __restrict__ We, const float* __restrict__ att,
                                  float* __restrict__ alpha, float* __restrict__ amax, int E) {
  int wid = (int)((blockIdx.x * (size_t)blockDim.x + threadIdx.x) >> 6);
  int lane = threadIdx.x & 63;
  if (wid >= E) return;
  int s = src[wid], d = dst[wid];
  float eav = ea[wid];
  const float* xls = xl + (size_t)s * 256;
  const float* xrd = xr + (size_t)d * 256;
#pragma unroll
  for (int h = 0; h < NH; ++h) {
    int c = h * 64 + lane;
    float v = xls[c] + xrd[c] + eav * We[c];
    v = (v >= 0.0f) ? v : 0.2f * v;   // leaky_relu(0.2)
    float p = v * att[c];
#pragma unroll
    for (int off = 32; off > 0; off >>= 1) p += __shfl_xor(p, off, 64);
    if (lane == 0) {
      alpha[(size_t)wid * NH + h] = p;
      atomicMaxFloat(&amax[(size_t)d * NH + h], p);
    }
  }
}

// ex = exp(alpha - amax[dst]); denom[dst,h] += ex  (alpha overwritten with ex)
__global__ void edge_softmax_kernel(const int* __restrict__ dst, const float* __restrict__ amax,
                                    float* __restrict__ alpha, float* __restrict__ denom, int E) {
  int idx = blockIdx.x * blockDim.x + threadIdx.x;
  if (idx >= E * NH) return;
  int e = idx >> 2, h = idx & 3;
  int d = dst[e];
  float ex = expf(alpha[idx] - amax[(size_t)d * NH + h]);
  alpha[idx] = ex;
  atomicAdd(&denom[(size_t)d * NH + h], ex);
}

// One wave per edge: out[dst,:] += xl[src,:] * (ex/(denom[dst]+1e-16))
__global__ void edge_scatter_kernel(const int* __restrict__ src, const int* __restrict__ dst,
                                    const float* __restrict__ xl, const float* __restrict__ ex,
                                    const float* __restrict__ denom, float* __restrict__ out, int E) {
  int wid = (int)((blockIdx.x * (size_t)blockDim.x + threadIdx.x) >> 6);
  int lane = threadIdx.x & 63;
  if (wid >= E) return;
  int s = src[wid], d = dst[wid];
  const float* xls = xl + (size_t)s * 256;
  float* outd = out + (size_t)d * 256;
#pragma unroll
  for (int h = 0; h < NH; ++h) {
    float a = ex[(size_t)wid * NH + h] / (denom[(size_t)d * NH + h] + 1e-16f);
    atomicAdd(&outd[h * 64 + lane], xls[h * 64 + lane] * a);
  }
}

__global__ void bias_relu_kernel(float* __restrict__ out, const float* __restrict__ bias, int N) {
  int idx = blockIdx.x * blockDim.x + threadIdx.x;
  if (idx >= N * 256) return;
  out[idx] = fmaxf(out[idx] + bias[idx & 255], 0.0f);
}

__global__ void pool_kernel(const float* __restrict__ h, const int* __restrict__ batch,
                            float* __restrict__ sums, float* __restrict__ cnt, int N) {
  int idx = blockIdx.x * blockDim.x + threadIdx.x;
  if (idx >= N * 256) return;
  int n = idx >> 8, c = idx & 255;
  int g = batch[n];
  atomicAdd(&sums[(size_t)g * 256 + c], h[idx]);
  if (c == 0) atomicAdd(&cnt[g], 1.0f);
}

// One block (128 thr) per graph: p -> z=p@p1W+b -> LN -> relu -> @p2W+b -> relu
__global__ void mlp_kernel(const float* __restrict__ sums, const float* __restrict__ cnt,
                           const float* __restrict__ p1W, const float* __restrict__ p1b,
                           const float* __restrict__ lng, const float* __restrict__ lnb,
                           const float* __restrict__ p2W, const float* __restrict__ p2b,
                           float* __restrict__ outp, int G) {
  __shared__ float p[256];
  __shared__ float z[128];
  __shared__ float wsum[2];
  __shared__ float wsum2[2];
  int g = blockIdx.x;
  int t = threadIdx.x;  // 0..127
  float c = fmaxf(cnt[g], 1.0f);
  p[t] = sums[(size_t)g * 256 + t] / c;
  p[t + 128] = sums[(size_t)g * 256 + t + 128] / c;
  __syncthreads();
  float acc = p1b[t];
  for (int k = 0; k < 256; ++k) acc = fmaf(p[k], p1W[k * 128 + t], acc);
  // LayerNorm over 128
  float v = acc;
#pragma unroll
  for (int off = 32; off > 0; off >>= 1) v += __shfl_xor(v, off, 64);
  if ((t & 63) == 0) wsum[t >> 6] = v;
  __syncthreads();
  float mu = (wsum[0] + wsum[1]) * (1.0f / 128.0f);
  float dv = acc - mu;
  float vv = dv * dv;
#pragma unroll
  for (int off = 32; off > 0; off >>= 1) vv += __shfl_xor(vv, off, 64);
  if ((t & 63) == 0) wsum2[t >> 6] = vv;
  __syncthreads();
  float var = (wsum2[0] + wsum2[1]) * (1.0f / 128.0f);
  float zv = dv * rsqrtf(var + 1e-5f) * lng[t] + lnb[t];
  z[t] = fmaxf(zv, 0.0f);
  __syncthreads();
  if (t < 64) {
    float o = p2b[t];
    for (int k = 0; k < 128; ++k) o = fmaf(z[k], p2W[k * 64 + t], o);
    outp[(size_t)g * 64 + t] = fmaxf(o, 0.0f);
  }
}

static void run_gat_layer(int K, const float* h,
                          const float* Wl, const float* bl,
                          const float* Wr, const float* br,
                          const float* We, const float* att, const float* bias,
                          const int* src, const int* dst, const float* ea,
                          float* xl, float* xr, float* alpha, float* amax, float* denom,
                          float* out, int N, int E, hipStream_t stream) {
  int nblk = (N + 7) / 8;
  if (K == 64)
    lin_lr_kernel<64><<<nblk, 256, 0, stream>>>(h, Wl, bl, Wr, br, xl, xr, N);
  else
    lin_lr_kernel<256><<<nblk, 256, 0, stream>>>(h, Wl, bl, Wr, br, xl, xr, N);
  hipMemsetAsync(amax, 0xFF, (size_t)N * NH * sizeof(float), stream);   // acts as -inf for atomicMaxFloat
  hipMemsetAsync(denom, 0, (size_t)N * NH * sizeof(float), stream);
  edge_alpha_kernel<<<(E + 3) / 4, 256, 0, stream>>>(src, dst, ea, xl, xr, We, att, alpha, amax, E);
  edge_softmax_kernel<<<(E * NH + 255) / 256, 256, 0, stream>>>(dst, amax, alpha, denom, E);
  hipMemsetAsync(out, 0, (size_t)N * 256 * sizeof(float), stream);      // h (input) no longer needed past lin_lr
  edge_scatter_kernel<<<(E + 3) / 4, 256, 0, stream>>>(src, dst, xl, alpha, denom, out, E);
  bias_relu_kernel<<<(N * 256 + 255) / 256, 256, 0, stream>>>(out, bias, N);
}

extern "C" void kernel_launch(void* const* d_in, const int* in_sizes, int n_in,
                              void* d_out, int out_size, void* d_ws, size_t ws_size,
                              hipStream_t stream) {
  const float* x      = (const float*)d_in[0];
  const int*   ei     = (const int*)d_in[1];
  const float* ea     = (const float*)d_in[2];
  const int*   batch  = (const int*)d_in[3];
  const float* enc_W  = (const float*)d_in[4];
  const float* enc_b  = (const float*)d_in[5];
  const float* Wl1    = (const float*)d_in[6];
  const float* bl1    = (const float*)d_in[7];
  const float* Wr1    = (const float*)d_in[8];
  const float* br1    = (const float*)d_in[9];
  const float* We1    = (const float*)d_in[10];
  const float* att1   = (const float*)d_in[11];
  const float* bias1  = (const float*)d_in[12];
  const float* Wl2    = (const float*)d_in[13];
  const float* bl2    = (const float*)d_in[14];
  const float* Wr2    = (const float*)d_in[15];
  const float* br2    = (const float*)d_in[16];
  const float* We2    = (const float*)d_in[17];
  const float* att2   = (const float*)d_in[18];
  const float* bias2  = (const float*)d_in[19];
  const float* p1W    = (const float*)d_in[20];
  const float* p1b    = (const float*)d_in[21];
  const float* lng    = (const float*)d_in[22];
  const float* lnb    = (const float*)d_in[23];
  const float* p2W    = (const float*)d_in[24];
  const float* p2b    = (const float*)d_in[25];
  float* outp = (float*)d_out;

  int N = in_sizes[0] / 8;
  int E = in_sizes[2];         // edge_attr is [E,1]
  int G = out_size / 64;
  const int* src = ei;
  const int* dst = ei + E;

  // workspace layout (floats)
  float* ws    = (float*)d_ws;
  float* h0    = ws;                        // N*64
  float* B0    = h0    + (size_t)N * 64;    // N*256 (xl)
  float* B1    = B0    + (size_t)N * 256;   // N*256 (xr)
  float* B2    = B1    + (size_t)N * 256;   // N*256 (layer out / next h)
  float* alpha = B2    + (size_t)N * 256;   // E*4 (alpha, then ex)
  float* amax  = alpha + (size_t)E * NH;    // N*4
  float* denom = amax  + (size_t)N * NH;    // N*4
  float* sums  = denom + (size_t)N * NH;    // G*256
  float* cnt   = sums  + (size_t)G * 256;   // G

  // encoder
  encoder_kernel<<<(N * 64 + 255) / 256, 256, 0, stream>>>(x, enc_W, enc_b, h0, N);

  // GAT layer 1 (K=64): h0 -> B2
  run_gat_layer(64, h0, Wl1, bl1, Wr1, br1, We1, att1, bias1,
                src, dst, ea, B0, B1, alpha, amax, denom, B2, N, E, stream);

  // GAT layer 2 (K=256): B2 -> B2 (B2 free after lin_lr; scatter rebuilds it)
  run_gat_layer(256, B2, Wl2, bl2, Wr2, br2, We2, att2, bias2,
                src, dst, ea, B0, B1, alpha, amax, denom, B2, N, E, stream);

  // global mean pool + MLP
  hipMemsetAsync(sums, 0, ((size_t)G * 256 + G) * sizeof(float), stream);
  pool_kernel<<<(N * 256 + 255) / 256, 256, 0, stream>>>(B2, batch, sums, cnt, N);
  mlp_kernel<<<G, 128, 0, stream>>>(sums, cnt, p1W, p1b, lng, lnb, p2W, p2b, outp, G);
}